// Round 4
// baseline (5548.974 us; speedup 1.0000x reference)
//
#include <hip/hip_runtime.h>

// ConditionalSmilesRnn: 3-layer LSTM, B=256, H=1024, steps=99, V=47, P=3.
// R4: barrier-free, LDS-free diag kernel. Weights pre-packed into
// MFMA-fragment-contiguous granules (64 lanes x 16B), loaded straight to
// VGPRs; h/x loaded per-lane from L2. Swapped-operand 32x32x16 MFMA puts
// all 4 gates of 8 hidden cols in-lane -> vectorized fused LSTM cell.
// 192 WGs x 8 independent waves (2/SIMD), manual 2-deep register pipeline.

typedef unsigned short u16;
typedef __bf16 bf16x8 __attribute__((ext_vector_type(8)));
typedef float f32x4 __attribute__((ext_vector_type(4)));
typedef float f32x16 __attribute__((ext_vector_type(16)));
typedef u16 u16x4 __attribute__((ext_vector_type(4)));
typedef u16 u16x8 __attribute__((ext_vector_type(8)));

#define MFMA16(a,b,c) __builtin_amdgcn_mfma_f32_16x16x32_bf16((a),(b),(c),0,0,0)
#define MFMA32(a,b,c) __builtin_amdgcn_mfma_f32_32x32x16_bf16((a),(b),(c),0,0,0)

__device__ __forceinline__ u16 f2bf(float f){
  unsigned u = __builtin_bit_cast(unsigned, f);
  u += 0x7fffu + ((u >> 16) & 1u);          // RN-even
  return (u16)(u >> 16);
}
__device__ __forceinline__ float bf2f(u16 s){
  unsigned u = ((unsigned)s) << 16;
  return __builtin_bit_cast(float, u);
}
__device__ __forceinline__ float sigm(float x){ return 1.f/(1.f+__expf(-x)); }
__device__ __forceinline__ float tanhfast(float x){ return 1.f - 2.f/(__expf(2.f*x)+1.f); }

// ---- f32 -> bf16 strided converter
__global__ void k_conv(const float* __restrict__ src, u16* __restrict__ dst,
                       long total, int srow, int sstride, int dstride, int doff){
  long i = ((long)blockIdx.x*blockDim.x + threadIdx.x)*8;
  if (i >= total) return;
  long r = i / srow;
  int  k = (int)(i - r*srow);
  const float* s = src + r*(long)sstride + k;
  u16x8 o;
  #pragma unroll
  for (int j=0;j<8;++j) o[j] = f2bf(s[j]);
  *(u16x8*)(dst + r*(long)dstride + doff + k) = o;
}

// ---- weight pack, L0 (K=1024, NC=16): fragment-granule order.
// piece index p: lane=p&63, kf=(p>>6)&3, nb=(p>>8)&3, kc=(p>>10)&15, jt=p>>14
// n' = jt*128+nb*32+(lane&31); k = kc*64+kf*16+(lane>>5)*8
// n  = ((n'>>4)&3)*1024 + (n'>>6)*16 + (n'&15)   (gate-interleave inverse)
__global__ void k_pack0(const float* __restrict__ W, u16* __restrict__ dst){
  long p = (long)blockIdx.x*256 + threadIdx.x;     // 2^19 pieces
  int lane = (int)(p & 63), kf = (int)((p>>6)&3), nb = (int)((p>>8)&3);
  int kc = (int)((p>>10)&15), jt = (int)(p>>14);
  int np = jt*128 + nb*32 + (lane&31);
  int k  = kc*64 + kf*16 + (lane>>5)*8;
  int n  = ((np>>4)&3)*1024 + (np>>6)*16 + (np&15);
  const float* s = W + (long)n*1024 + k;
  u16x8 o;
  #pragma unroll
  for (int j=0;j<8;++j) o[j] = f2bf(s[j]);
  *(u16x8*)(dst + p*8) = o;
}

// ---- weight pack, L1/2 (K=2048, NC=32): k<1024 from W_ih_r, else W_hh_r
__global__ void k_pack12(const float* __restrict__ Wih, const float* __restrict__ Whh,
                         u16* __restrict__ dst){
  long p = (long)blockIdx.x*256 + threadIdx.x;     // 2*2^20 pieces
  int lane = (int)(p & 63), kf = (int)((p>>6)&3), nb = (int)((p>>8)&3);
  int kc = (int)((p>>10)&31), jt = (int)((p>>15)&31);
  long l = p >> 20;
  int np = jt*128 + nb*32 + (lane&31);
  int k  = kc*64 + kf*16 + (lane>>5)*8;
  int n  = ((np>>4)&3)*1024 + (np>>6)*16 + (np&15);
  const float* s = (k < 1024) ? Wih + ((long)l*4096 + n)*1024 + k
                              : Whh + ((long)l*4096 + n)*1024 + (k - 1024);
  u16x8 o;
  #pragma unroll
  for (int j=0;j<8;++j) o[j] = f2bf(s[j]);
  *(u16x8*)(dst + p*8) = o;
}

// ---- misc prep: biases, pad-row zeroing, state init, gx_prop (+bias0 folded)
__global__ void k_misc(const float* __restrict__ b_ih0, const float* __restrict__ b_hh0,
                       const float* __restrict__ b_ihr, const float* __restrict__ b_hhr,
                       const float* __restrict__ h0, const float* __restrict__ c0,
                       const float* __restrict__ props, const float* __restrict__ W_ih0,
                       u16* __restrict__ Ebf, u16* __restrict__ Wdec,
                       float* __restrict__ bcat,
                       u16* __restrict__ hbf0, float* __restrict__ cst, float* __restrict__ gxp){
  long i = (long)blockIdx.x*256 + threadIdx.x;
  if (i < 2*4096){ bcat[i] = b_ihr[i] + b_hhr[i]; return; }
  i -= 2*4096;
  if (i < 1024){ Ebf[47*1024 + i] = 0; Wdec[47*1024 + i] = 0; return; }
  i -= 1024;
  if (i < (long)3*256*1024){ hbf0[i] = f2bf(h0[i]); cst[i] = c0[i]; return; }
  i -= (long)3*256*1024;
  if (i < (long)256*4096){
    int b = (int)(i >> 12), n = (int)(i & 4095);
    const float* wr = W_ih0 + (long)n*1027 + 1024;
    gxp[i] = props[b*3+0]*wr[0] + props[b*3+1]*wr[1] + props[b*3+2]*wr[2]
           + b_ih0[n] + b_hh0[n];
  }
}

// ---- gx_emb[v][n] = sum_k E[v][k] * W_ih0[n][k]  (M=48 padded, N=4096, K=1024)
__global__ __launch_bounds__(64)
void k_gxemb(const u16* __restrict__ Ebf, const u16* __restrict__ Wih0b, float* __restrict__ gxe){
  const int lane = threadIdx.x;
  const int cl = lane & 15, ko = (lane >> 4)*8;
  const int m0 = blockIdx.x*16;
  const int n0 = blockIdx.y*16;
  f32x4 acc = {0.f,0.f,0.f,0.f};
  const u16* ap = Ebf   + (size_t)(m0+cl)*1024 + ko;
  const u16* bp = Wih0b + (size_t)(n0+cl)*1024 + ko;
  for (int k0=0; k0<1024; k0+=32){
    bf16x8 a = *(const bf16x8*)(ap + k0);
    bf16x8 b = *(const bf16x8*)(bp + k0);
    acc = MFMA16(a, b, acc);
  }
  const int rbase = (lane >> 4)*4;
  #pragma unroll
  for (int q=0;q<4;++q){
    int v = m0 + rbase + q;
    if (v < 47) gxe[(size_t)v*4096 + n0 + cl] = acc[q];
  }
}

// ---- diag kernel: 192 WGs x 512 thr. WG tile: 128 batch x 128 weight-rows.
// 8 waves = 4 batch-blocks(32) x 2 rowpair-blocks(64). No LDS, no barriers.
template<int LAYER>
__device__ __forceinline__ void diag_tile(int mt, int jt, int t,
    const int* __restrict__ x, u16* __restrict__ hbf, u16* __restrict__ outsb,
    float* __restrict__ cst, const u16* __restrict__ Wpk0, const u16* __restrict__ Wpk12,
    const float* __restrict__ bcat, const float* __restrict__ gxe,
    const float* __restrict__ gxp)
{
  constexpr int KT = (LAYER==0) ? 1024 : 2048;
  constexpr int NC = KT/64;
  const int tid = threadIdx.x;
  const int lane = tid & 63, wv = tid >> 6;
  const int wm = wv >> 1, wn = wv & 1;
  const int l31 = lane & 31, hi5 = lane >> 5;
  const size_t BH = (size_t)256*1024;
  const int p = t & 1;

  const u16* hp = hbf + ((size_t)p*3 + LAYER)*BH;       // own h @ t-1
  u16*       hn = hbf + ((size_t)(p^1)*3 + LAYER)*BH;   // own h @ t
  float*     cc = cst + (size_t)LAYER*BH;
  const u16* xb = (LAYER>0) ? hbf + ((size_t)(p^1)*3 + (LAYER-1))*BH : (const u16*)0;
  const u16* Wlay = (LAYER==0) ? Wpk0 : Wpk12 + (size_t)(LAYER-1)*4096*2048;

  const int m = mt*128 + wm*32 + l31;                   // this lane's batch row
  // A-side (h/x) per-lane base: row m, within-row offset hi5*8
  const u16* arow_x = (LAYER>0) ? xb + (size_t)m*1024 + hi5*8 : (const u16*)0;
  const u16* arow_h = hp + (size_t)m*1024 + hi5*8;

  f32x16 acc0, acc1;
  #pragma unroll
  for (int i=0;i<16;++i){ acc0[i]=0.f; acc1[i]=0.f; }

  bf16x8 W0[2][4], H0[4], W1[2][4], H1[4];

  auto loadW = [&](bf16x8 wf[2][4], int kc){
    const size_t base = ((size_t)(jt*NC + kc)*16)*512 + (size_t)lane*8;
    #pragma unroll
    for (int nb2=0; nb2<2; ++nb2)
      #pragma unroll
      for (int kf=0; kf<4; ++kf)
        wf[nb2][kf] = *(const bf16x8*)(Wlay + base + (size_t)((2*wn+nb2)*4 + kf)*512);
  };
  auto loadH = [&](bf16x8 hf[4], int kc){
    const int kg = kc*64;
    const u16* pa;
    if (LAYER > 0) pa = (kg < 1024) ? arow_x + kg : arow_h + (kg - 1024);
    else           pa = arow_h + kg;
    #pragma unroll
    for (int kf=0; kf<4; ++kf)
      hf[kf] = *(const bf16x8*)(pa + kf*16);
  };

  loadW(W0, 0); loadH(H0, 0);
  for (int kc = 0; kc < NC; kc += 2){
    loadW(W1, kc+1); loadH(H1, kc+1);
    #pragma unroll
    for (int kf=0; kf<4; ++kf){
      acc0 = MFMA32(W0[0][kf], H0[kf], acc0);
      acc1 = MFMA32(W0[1][kf], H0[kf], acc1);
    }
    if (kc+2 < NC){ loadW(W0, kc+2); loadH(H0, kc+2); }
    #pragma unroll
    for (int kf=0; kf<4; ++kf){
      acc0 = MFMA32(W1[0][kf], H1[kf], acc0);
      acc1 = MFMA32(W1[1][kf], H1[kf], acc1);
    }
  }

  // Epilogue. Swapped-operand C/D: col=lane&31 -> batch (m), reg r ->
  // weight-row offset wr = (r&3)+8*(r>>2)+4*hi5 within the 32-block.
  // acc0 = rows [wn*64, +32): i (wr<16), f (wr>=16); acc1 = +32: g, o.
  // Lane covers hlo = a*8 + hi5*4 + b, a in {0,1}, b in {0..3}:
  //   gi=acc0[a*4+b], gf=acc0[8+a*4+b], gg=acc1[a*4+b], go=acc1[8+a*4+b]
  const int hbl = (jt*2 + wn)*16 + hi5*4;
  float* crow = cc + (size_t)m*1024;
  u16*   hrow = hn + (size_t)m*1024;
  u16*   orow = (LAYER==2) ? outsb + (size_t)t*BH + (size_t)m*1024 : (u16*)0;
  const float* gerow = (const float*)0;
  const float* gprow = (const float*)0;
  if (LAYER == 0){
    const int tok = (t==0) ? 1 : x[m*100 + t];
    gerow = gxe + (size_t)tok*4096;
    gprow = gxp + (size_t)m*4096;
  }
  const float* bias = bcat + (size_t)(LAYER>0 ? LAYER-1 : 0)*4096;
  #pragma unroll
  for (int a=0; a<2; ++a){
    const int hc = hbl + a*8;
    f32x4 gi, gf, gg, go;
    #pragma unroll
    for (int b=0; b<4; ++b){
      gi[b] = acc0[a*4+b]; gf[b] = acc0[8+a*4+b];
      gg[b] = acc1[a*4+b]; go[b] = acc1[8+a*4+b];
    }
    if (LAYER == 0){
      gi += *(const f32x4*)(gerow + hc)        + *(const f32x4*)(gprow + hc);
      gf += *(const f32x4*)(gerow + 1024 + hc) + *(const f32x4*)(gprow + 1024 + hc);
      gg += *(const f32x4*)(gerow + 2048 + hc) + *(const f32x4*)(gprow + 2048 + hc);
      go += *(const f32x4*)(gerow + 3072 + hc) + *(const f32x4*)(gprow + 3072 + hc);
    } else {
      gi += *(const f32x4*)(bias + hc);
      gf += *(const f32x4*)(bias + 1024 + hc);
      gg += *(const f32x4*)(bias + 2048 + hc);
      go += *(const f32x4*)(bias + 3072 + hc);
    }
    f32x4 cold = *(const f32x4*)(crow + hc);
    f32x4 cnew;
    u16x4 hb;
    #pragma unroll
    for (int b=0; b<4; ++b){
      const float i_ = sigm(gi[b]), f_ = sigm(gf[b]), o_ = sigm(go[b]);
      const float g_ = tanhfast(gg[b]);
      const float cn = f_*cold[b] + i_*g_;
      cnew[b] = cn;
      hb[b] = f2bf(o_*tanhfast(cn));
    }
    *(f32x4*)(crow + hc) = cnew;
    *(u16x4*)(hrow + hc) = hb;
    if (LAYER == 2) *(u16x4*)(orow + hc) = hb;
  }
}

// grid = 192: id = mt*96 + layer*32 + jt  (id%8 = jt%8, stable across
// dispatches and shared by both mt copies -> weight slice pinned per XCD)
__global__ __launch_bounds__(512, 2)
void k_diag(int d, const int* __restrict__ x, u16* __restrict__ hbf,
            u16* __restrict__ outsb, float* __restrict__ cst,
            const u16* __restrict__ Wpk0, const u16* __restrict__ Wpk12,
            const float* __restrict__ bcat,
            const float* __restrict__ gxe, const float* __restrict__ gxp)
{
  const int id = blockIdx.x;
  const int mt = id / 96;
  const int s  = id - mt*96;
  const int layer = s >> 5;
  const int jt = s & 31;
  const int t = d - layer;
  if (t < 0 || t >= 99) return;
  if (layer == 0)
    diag_tile<0>(mt, jt, t, x, hbf, outsb, cst, Wpk0, Wpk12, bcat, gxe, gxp);
  else if (layer == 1)
    diag_tile<1>(mt, jt, t, x, hbf, outsb, cst, Wpk0, Wpk12, bcat, gxe, gxp);
  else
    diag_tile<2>(mt, jt, t, x, hbf, outsb, cst, Wpk0, Wpk12, bcat, gxe, gxp);
}

// ---- decoder: logits[b,t,v] = outs[t,b,:] . Wdec[v,:] + b_dec[v]
__global__ __launch_bounds__(256)
void k_decode(const u16* __restrict__ outs, const u16* __restrict__ Wdec,
              const float* __restrict__ bdec, float* __restrict__ logits){
  const int lane = threadIdx.x & 63, w = threadIdx.x >> 6;
  const int cl = lane & 15, ko = (lane >> 4)*8;
  const size_t m0 = ((size_t)blockIdx.x*4 + w)*16;
  const u16* ap = outs + (m0+cl)*1024 + ko;
  f32x4 acc[3];
  #pragma unroll
  for (int nt=0; nt<3; ++nt) acc[nt] = (f32x4){0.f,0.f,0.f,0.f};
  const u16* bp = Wdec + (size_t)cl*1024 + ko;
  for (int k0=0; k0<1024; k0+=32){
    bf16x8 a = *(const bf16x8*)(ap + k0);
    #pragma unroll
    for (int nt=0; nt<3; ++nt){
      bf16x8 b = *(const bf16x8*)(bp + (size_t)nt*16*1024 + k0);
      acc[nt] = MFMA16(a, b, acc[nt]);
    }
  }
  const int rbase = (lane >> 4)*4;
  #pragma unroll
  for (int nt=0; nt<3; ++nt){
    #pragma unroll
    for (int q=0; q<4; ++q){
      int v = nt*16 + cl;
      if (v < 47){
        size_t row = m0 + rbase + q;   // row = t*256 + b
        int tt = (int)(row >> 8);
        int b  = (int)(row & 255);
        logits[((size_t)b*99 + tt)*47 + v] = acc[nt][q] + bdec[v];
      }
    }
  }
}

// ---- final hT / cT copy-out
__global__ void k_final(const u16* __restrict__ hb, const float* __restrict__ cst, float* __restrict__ out){
  int i = blockIdx.x*256 + threadIdx.x;
  if (i < 3*256*1024){
    out[1191168 + i]          = bf2f(hb[i]);
    out[1191168 + 786432 + i] = cst[i];
  }
}

extern "C" void kernel_launch(void* const* d_in, const int* in_sizes, int n_in,
                              void* d_out, int out_size, void* d_ws, size_t ws_size,
                              hipStream_t stream) {
  (void)in_sizes; (void)n_in; (void)out_size; (void)ws_size;
  const int*   x      = (const int*)  d_in[0];
  const float* props  = (const float*)d_in[1];
  const float* h0     = (const float*)d_in[2];
  const float* c0     = (const float*)d_in[3];
  const float* E      = (const float*)d_in[4];
  const float* W_ih0  = (const float*)d_in[5];
  const float* W_hh0  = (const float*)d_in[6];
  const float* b_ih0  = (const float*)d_in[7];
  const float* b_hh0  = (const float*)d_in[8];
  const float* W_ih_r = (const float*)d_in[9];
  const float* W_hh_r = (const float*)d_in[10];
  const float* b_ih_r = (const float*)d_in[11];
  const float* b_hh_r = (const float*)d_in[12];
  const float* W_dec  = (const float*)d_in[13];
  const float* b_dec  = (const float*)d_in[14];
  float* out = (float*)d_out;

  // workspace layout (~110 MB)
  u16* Wpk0  = (u16*)d_ws;                          // 4096*1024   (frag-packed L0)
  u16* Wpk12 = Wpk0  + (size_t)4096*1024;           // 2*4096*2048 (frag-packed L1/2)
  u16* Wdec  = Wpk12 + (size_t)2*4096*2048;         // 48*1024 (row 47 = 0)
  u16* Wih0b = Wdec  + (size_t)48*1024;             // 4096*1024 (first 1024 cols of W_ih0)
  u16* Ebf   = Wih0b + (size_t)4096*1024;           // 48*1024 (row 47 = 0)
  u16* hbf   = Ebf   + (size_t)48*1024;             // 2 * 3*256*1024 (dbuf h, bf16)
  u16* outsb = hbf   + (size_t)2*3*256*1024;        // 99*256*1024
  float* gxe   = (float*)(outsb + (size_t)99*256*1024); // 47*4096
  float* gxp   = gxe   + (size_t)47*4096;               // 256*4096 (bias0 folded in)
  float* bcat  = gxp   + (size_t)256*4096;              // 2*4096
  float* cst   = bcat  + 2*4096;                        // 3*256*1024 f32

  // ---- prep
  k_pack0 <<<2048, 256, 0, stream>>>(W_hh0, Wpk0);
  k_pack12<<<8192, 256, 0, stream>>>(W_ih_r, W_hh_r, Wpk12);
  k_conv<<<2048, 256, 0, stream>>>(W_ih0,  Wih0b, (long)4096*1024, 1024, 1027, 1024, 0);
  k_conv<<<24,   256, 0, stream>>>(E,      Ebf,   (long)47*1024,   1024, 1024, 1024, 0);
  k_conv<<<24,   256, 0, stream>>>(W_dec,  Wdec,  (long)47*1024,   1024, 1024, 1024, 0);
  k_misc<<<7205, 256, 0, stream>>>(b_ih0, b_hh0, b_ih_r, b_hh_r, h0, c0, props, W_ih0,
                                   Ebf, Wdec, bcat, hbf, cst, gxp);
  k_gxemb<<<dim3(3,256), 64, 0, stream>>>(Ebf, Wih0b, gxe);

  // ---- diagonal recurrence: dispatch d runs (L0@d, L1@d-1, L2@d-2)
  for (int d = 0; d < 101; ++d){
    k_diag<<<192, 512, 0, stream>>>(d, x, hbf, outsb, cst,
                                    Wpk0, Wpk12, bcat, gxe, gxp);
  }

  // ---- decode + final states (last write at t=98 -> state buffer 1)
  k_decode<<<396, 256, 0, stream>>>(outsb, Wdec, b_dec, out);
  k_final<<<3072, 256, 0, stream>>>(hbf + (size_t)3*256*1024, cst, out);
}